// Round 11
// baseline (139.201 us; speedup 1.0000x reference)
//
#include <hip/hip_runtime.h>
#include <stdint.h>

typedef __attribute__((ext_vector_type(8))) short short8;
typedef __attribute__((ext_vector_type(4))) float f32x4;

#define NH 12
#define DH 64

// 2 x f32 -> packed 2 x bf16 (RNE) in one instruction
__device__ __forceinline__ uint32_t cvtpk(float lo, float hi) {
  uint32_t r;
  asm("v_cvt_pk_bf16_f32 %0, %1, %2" : "=v"(r) : "v"(lo), "v"(hi));
  return r;
}

typedef const __attribute__((address_space(1))) uint32_t gu32;
typedef __attribute__((address_space(3))) uint32_t lu32;

__device__ __forceinline__ void gll16(const void* src, void* lds) {
  __builtin_amdgcn_global_load_lds((gu32*)(uintptr_t)src, (lu32*)(uintptr_t)lds, 16, 0, 0);
}

// Per-head base offset in u32 units inside Kb / Vt workspace arrays.
// heads 0-3: r=1 Sd=8192; 4-7: r=2 Sd=4096; 8-11: r=4 Sd=2048; 32 u32/row.
__device__ __forceinline__ int head_base2(int h) {
  return (h < 4) ? (h << 18)
       : (h < 8) ? ((1 << 20) + ((h - 4) << 17))
                 : ((1 << 20) + (1 << 19) + ((h - 8) << 16));
}

// ------------- merged prepass: K gather->bf16, V gather->bf16 transposed ----
// bids [0,7168): K part (1,835,008 u32 pairs). bids [7168,8064): V part.
__global__ __launch_bounds__(256)
void prep(const float* __restrict__ K, const float* __restrict__ V,
          uint32_t* __restrict__ Kb, short* __restrict__ Vt) {
  __shared__ short T[64][72];   // V part only; pad 72 keeps 16B alignment
  const int bid = blockIdx.x, tid = threadIdx.x;
  if (bid < 7168) {
    const int p = bid * 256 + tid;
    int h, r, off, sh, rem;
    if (p < 1048576)      { h = p >> 18;                    rem = p & 262143; r = 1; off = 0; sh = 9; }
    else if (p < 1572864) { int q = p - 1048576; h = 4 + (q >> 17); rem = q & 131071; r = 2; off = 1; sh = 8; }
    else                  { int q = p - 1572864; h = 8 + (q >> 16); rem = q & 65535;  r = 4; off = 2; sh = 7; }
    const int i = rem >> 5, d2 = rem & 31;
    const int j = i & ((1 << sh) - 1), b = i >> sh;
    const int tok = b * 512 + off + r * j;
    const float2 f = *reinterpret_cast<const float2*>(K + ((size_t)tok * NH + h) * DH + d2 * 2);
    Kb[p] = cvtpk(f.x, f.y);
  } else {
    const int vb = bid - 7168;
    int h, r, off, SDB, b, tile;
    if (vb < 512)      { h = vb >> 7;            int rem = vb & 127; b = rem >> 3; tile = rem & 7; r = 1; off = 0; SDB = 512; }
    else if (vb < 768) { int t2 = vb - 512; h = 4 + (t2 >> 6); int rem = t2 & 63; b = rem >> 2; tile = rem & 3; r = 2; off = 1; SDB = 256; }
    else               { int t3 = vb - 768; h = 8 + (t3 >> 5); int rem = t3 & 31; b = rem >> 1; tile = rem & 1; r = 4; off = 2; SDB = 128; }
    const int jj0 = tile * 64;
    const int dl = (tid & 15) * 4, tl0 = tid >> 4;
    #pragma unroll
    for (int rep = 0; rep < 4; ++rep) {
      const int tokl = rep * 16 + tl0;
      const int tok = b * 512 + off + r * (jj0 + tokl);
      const float4 f = *reinterpret_cast<const float4*>(V + ((size_t)tok * NH + h) * DH + dl);
      const uint32_t u01 = cvtpk(f.x, f.y), u23 = cvtpk(f.z, f.w);
      T[dl + 0][tokl] = (short)(u01 & 0xffffu);
      T[dl + 1][tokl] = (short)(u01 >> 16);
      T[dl + 2][tokl] = (short)(u23 & 0xffffu);
      T[dl + 3][tokl] = (short)(u23 >> 16);
    }
    __syncthreads();
    const size_t hbase = (size_t)head_base2(h) * 2;
    #pragma unroll
    for (int cc = 0; cc < 2; ++cc) {
      const int c = tid * 2 + cc, d = c >> 3, s = c & 7;
      short8 v = *reinterpret_cast<const short8*>(&T[d][s * 8]);
      *reinterpret_cast<short8*>(Vt + hbase + (size_t)(b * 64 + d) * SDB + jj0 + s * 8) = v;
    }
  }
}

// ------------------------------ main kernel --------------------------------
// 4-wave block = BOTH 64-row j-halves of one (rb, h, 128-col tile): the two
// halves read IDENTICAL K/V tiles, so merging halves staging traffic.
// Double-buffered LDS (2-phase): per cb iter, one __syncthreads (drains the
// in-flight global_load_lds + syncs), then issue next tile's loads, then
// compute current tile -> staging latency hides under compute.
template<int M, int R>
__device__ __forceinline__ void unit(
    const float* __restrict__ Q, float* __restrict__ Out,
    const char* __restrict__ KbB, const char* __restrict__ VtB,
    int rb, int h, int jc0, char* lds)
{
  constexpr int OFF    = (R == 1) ? 0 : ((R == 2) ? 1 : 2);
  constexpr int SDB    = 512 / R;
  constexpr int NT     = M / 16;
  constexpr int HALVES = (M == 128) ? 2 : 1;
  constexpr int TTP    = NT / HALVES;
  constexpr int KKP    = (M == 128) ? 2 : 1;
  constexpr int PROW   = (M == 128) ? 64 : 32;
  constexpr int PMASK  = (M == 128) ? 7 : 3;

  const char* kbh = KbB + (size_t)head_base2(h) * 4;
  const char* vth = VtB + (size_t)head_base2(h) * 4;

  const int tid = threadIdx.x, w = tid >> 6, lane = tid & 63;
  const int lhi = lane >> 4, llo = lane & 15;
  short* const P = (short*)(lds + 65536 + w * 2048);

  // Q fragments for both row-sets, scale log2(e)/8 folded in
  short8 qf[2][2];
  #pragma unroll
  for (int s = 0; s < 2; ++s) {
    const float SCL = 0.18033688f;
    const int tok = rb * 512 + OFF + R * (jc0 + s * 64 + w * 16 + llo);
    const float* src = Q + ((size_t)tok * NH + h) * DH + lhi * 8;
    float4 a0 = *reinterpret_cast<const float4*>(src);
    float4 a1 = *reinterpret_cast<const float4*>(src + 4);
    float4 b0 = *reinterpret_cast<const float4*>(src + 32);
    float4 b1 = *reinterpret_cast<const float4*>(src + 36);
    union { uint32_t u[4]; short8 v; } x0, x1;
    x0.u[0] = cvtpk(a0.x * SCL, a0.y * SCL); x0.u[1] = cvtpk(a0.z * SCL, a0.w * SCL);
    x0.u[2] = cvtpk(a1.x * SCL, a1.y * SCL); x0.u[3] = cvtpk(a1.z * SCL, a1.w * SCL);
    x1.u[0] = cvtpk(b0.x * SCL, b0.y * SCL); x1.u[1] = cvtpk(b0.z * SCL, b0.w * SCL);
    x1.u[2] = cvtpk(b1.x * SCL, b1.y * SCL); x1.u[3] = cvtpk(b1.z * SCL, b1.w * SCL);
    qf[s][0] = x0.v; qf[s][1] = x1.v;
  }

  f32x4 acc[2][4];
  #pragma unroll
  for (int s = 0; s < 2; ++s)
    #pragma unroll
    for (int dt = 0; dt < 4; ++dt) acc[s][dt] = f32x4{0.f, 0.f, 0.f, 0.f};

  const int c0 = (rb - 2 < 0) ? 0 : rb - 2;
  const int c1 = (rb + 2 > 15) ? 15 : rb + 2;
  const int nc = c1 - c0 + 1;

  // stage one 32 KB tile (K 16K + V 16K) into buffer pb; 8 gll16 per thread
  auto STAGE = [&](int pb, int cb) {
    char* Kd = lds + pb * 32768;
    char* Vd = Kd + 16384;
    #pragma unroll
    for (int n = 0; n < 4; ++n) {
      const int seg = n * 4 + w;
      const int ck = seg * 64 + lane;
      { const int t = ck >> 3, sp = ck & 7;
        gll16(kbh + (size_t)(cb * SDB + jc0 + t) * 128 + ((sp ^ (t & 7)) << 4),
              Kd + seg * 1024); }
      { const int d = ck >> 4, sp = ck & 15;
        gll16(vth + ((size_t)(cb * 64 + d) * SDB + jc0 + ((sp ^ (d & 15)) << 3)) * 2,
              Vd + seg * 1024); }
    }
  };

  STAGE(0, c0);
  int cur = 0;
  for (int ci = 0; ci < nc; ++ci) {
    __syncthreads();   // drains vmcnt (buf[cur] staged) + all waves done prev compute
    if (ci + 1 < nc) STAGE(cur ^ 1, c0 + ci + 1);
    const char* Klds = lds + cur * 32768;
    const char* Vlds = Klds + 16384;

    #pragma unroll
    for (int s = 0; s < 2; ++s) {
      const int c_lo = (M == 128) ? 0 : (s * 64 + (w >> 1) * 32);
      // ---- QK^T ----
      f32x4 sc[NT];
      #pragma unroll
      for (int tt = 0; tt < NT; ++tt) sc[tt] = f32x4{0.f, 0.f, 0.f, 0.f};
      #pragma unroll
      for (int kk = 0; kk < 2; ++kk) {
        #pragma unroll
        for (int tt = 0; tt < NT; ++tt) {
          const int t = c_lo + tt * 16 + llo;
          const int slot = (4 * kk + lhi) ^ (t & 7);
          short8 kf = *reinterpret_cast<const short8*>(Klds + t * 128 + slot * 16);
          sc[tt] = __builtin_amdgcn_mfma_f32_16x16x32_bf16(qf[s][kk], kf, sc[tt], 0, 0, 0);
        }
      }
      // ---- softmax (no max pass: scores bounded, shift-invariant) ----
      float sm[4] = {0.f, 0.f, 0.f, 0.f};
      #pragma unroll
      for (int tt = 0; tt < NT; ++tt)
        #pragma unroll
        for (int i = 0; i < 4; ++i) {
          const float p = exp2f(sc[tt][i]);
          sc[tt][i] = p;
          sm[i] += p;
        }
      #pragma unroll
      for (int i = 0; i < 4; ++i) {
        sm[i] += __shfl_xor(sm[i], 1);
        sm[i] += __shfl_xor(sm[i], 2);
        sm[i] += __shfl_xor(sm[i], 4);
        sm[i] += __shfl_xor(sm[i], 8);
        sm[i] = 1.0f / sm[i];
      }
      // ---- per-half: P -> per-wave LDS buffer, then PV ----
      #pragma unroll
      for (int h2 = 0; h2 < HALVES; ++h2) {
        #pragma unroll
        for (int ttl = 0; ttl < TTP; ++ttl) {
          const int tt = h2 * TTP + ttl;
          #pragma unroll
          for (int ip = 0; ip < 2; ++ip) {
            const uint32_t pk = cvtpk(sc[tt][2 * ip] * sm[2 * ip],
                                      sc[tt][2 * ip + 1] * sm[2 * ip + 1]);
            const int q0 = 4 * lhi + 2 * ip;
            const int chunk = 2 * ttl + (llo >> 3);
            P[q0 * PROW + ((chunk ^ (q0 & PMASK)) << 3) + (llo & 7)] = (short)(pk & 0xffffu);
            P[(q0 + 1) * PROW + ((chunk ^ ((q0 + 1) & PMASK)) << 3) + (llo & 7)] = (short)(pk >> 16);
          }
        }
        #pragma unroll
        for (int kkl = 0; kkl < KKP; ++kkl) {
          const int pch = (KKP == 2) ? (4 * kkl + lhi) : lhi;
          short8 pf = *reinterpret_cast<const short8*>(
              (const short*)P + llo * PROW + ((pch ^ (llo & PMASK)) << 3));
          #pragma unroll
          for (int dt = 0; dt < 4; ++dt) {
            const int d = dt * 16 + llo;
            const int lc = (M == 128) ? (8 * h2 + 4 * kkl + lhi) : (c_lo / 8 + lhi);
            short8 vf = *reinterpret_cast<const short8*>(
                Vlds + d * 256 + ((lc ^ (d & 15)) << 4));
            acc[s][dt] = __builtin_amdgcn_mfma_f32_16x16x32_bf16(pf, vf, acc[s][dt], 0, 0, 0);
          }
        }
      }
    }
    cur ^= 1;
  }

  // ---- epilogue: one plain store per covered element ----
  #pragma unroll
  for (int s = 0; s < 2; ++s) {
    #pragma unroll
    for (int i = 0; i < 4; ++i) {
      const int tok = rb * 512 + OFF + R * (jc0 + s * 64 + w * 16 + lhi * 4 + i);
      float* dst = Out + ((size_t)tok * NH + h) * DH;
      #pragma unroll
      for (int dt = 0; dt < 4; ++dt)
        dst[dt * 16 + llo] = acc[s][dt][i];
    }
  }
  // ---- zero-stores for non-dilated phases (replaces memset) ----
  if (R > 1) {
    #pragma unroll
    for (int s = 0; s < 2; ++s) {
      for (int ri = 0; ri < 16; ++ri) {
        const int tok = rb * 512 + OFF + R * (jc0 + s * 64 + w * 16 + ri);
        #pragma unroll
        for (int p = 0; p < R - 1; ++p) {
          const int dz = (R == 2) ? -1 : ((p == 0) ? -2 : ((p == 1) ? -1 : 1));
          Out[((size_t)(tok + dz) * NH + h) * DH + lane] = 0.f;
        }
      }
    }
  }
}

// Grid 448 blocks x 256 threads. XCD-aware: bid%8 = XCD; each XCD owns whole
// (head, tile) groups so cb tiles stay in its private L2 across consumers.
//   per XCD x (56 blocks): i<32 -> A-groups g={2x,2x+1} (16 rb each);
//   i in [32,48) -> B-group (h=4+(x>>1), jc0=(x&1)*128), rb=i-32;
//   i in [48,56) -> C head 8+(x>>1), rb = (i-48)+(x&1)*8.
__global__ __launch_bounds__(256, 2)
void bsda(const float* __restrict__ Q, float* __restrict__ Out,
          const char* __restrict__ Kb, const char* __restrict__ Vt) {
  __shared__ __align__(16) char lds[73728];  // 2 x (K 16K | V 16K) | P 4x2K
  const int x = blockIdx.x & 7;
  const int i = blockIdx.x >> 3;   // 0..55
  if (i < 32) {
    const int g = x * 2 + (i >> 4);
    unit<128, 1>(Q, Out, Kb, Vt, i & 15, g >> 2, (g & 3) * 128, lds);
  } else if (i < 48) {
    unit<128, 2>(Q, Out, Kb, Vt, i - 32, 4 + (x >> 1), (x & 1) * 128, lds);
  } else {
    unit<32, 4>(Q, Out, Kb, Vt, (i - 48) + (x & 1) * 8, 8 + (x >> 1), 0, lds);
  }
}

extern "C" void kernel_launch(void* const* d_in, const int* in_sizes, int n_in,
                              void* d_out, int out_size, void* d_ws, size_t ws_size,
                              hipStream_t stream) {
  const float* q = (const float*)d_in[0];
  const float* k = (const float*)d_in[1];
  const float* v = (const float*)d_in[2];
  float* out = (float*)d_out;

  uint32_t* Kb = (uint32_t*)d_ws;                          // 7,340,032 B
  short*    Vt = (short*)((char*)d_ws + 7340032);          // 7,340,032 B

  prep<<<dim3(8064), dim3(256), 0, stream>>>(k, v, Kb, Vt);
  bsda<<<dim3(448),  dim3(256), 0, stream>>>(q, out, (const char*)Kb, (const char*)Vt);
}